// Round 10
// baseline (85.958 us; speedup 1.0000x reference)
//
#include <hip/hip_runtime.h>
#include <hip/hip_cooperative_groups.h>
#include <cstddef>

namespace cg = cooperative_groups;

// Problem constants (from reference)
constexpr int Bn = 64;     // batch
constexpr int In = 2048;   // input capsules
constexpr int Dk = 8;      // input dim
constexpr int Kc = 16;     // output capsules
constexpr int En = 16;     // output dim
constexpr float EPS = 1e-7f;

// Decomposition (R8-proven balance): block = (p, g) tile of 8 i's x 16
// batches; wave owns 4 batches x all 8 i's -> disjoint outputs, barrier-free.
constexpr int IB   = 8;            // i's per block
constexpr int P    = In / IB;      // 256 i-chunks
constexpr int BSET = 16;           // batches per block (4 per wave)
constexpr int NBG  = Bn / BSET;    // 4 batch groups
constexpr int BLOCKS = P * NBG;    // 1024
constexpr int PPX  = P / 8;        // 32 p-chunks per XCD (2 MB of W < 4 MB L2)

// DPP cross-lane add on the VALU pipe (no LDS-pipe traffic).
template<int CTRL>
__device__ __forceinline__ float dpp_add(float v) {
    int r = __builtin_amdgcn_update_dpp(0, __float_as_int(v), CTRL, 0xF, 0xF, true);
    return v + __int_as_float(r);
}

// Load W[i, k, d, 0..3 at e4] into 8 float4 registers (static destination).
__device__ __forceinline__ void load_w(float4 (&w)[8], const float* __restrict__ W,
                                       int i, int k, int e4) {
    const float* wp = W + (size_t)i * (Kc * Dk * En) + k * (Dk * En) + e4;
    #pragma unroll
    for (int d = 0; d < 8; ++d) w[d] = *(const float4*)(wp + d * En);
}

// One routing iteration for a (p, g) tile. Wave wv handles batches bw..bw+3
// across all 8 i's; acc[4] = 16 VGPR (R4/R5 lesson: live set structurally
// small, all indices static, NO launch_bounds VGPR cap).
// x is read via WAVE-UNIFORM addresses (readfirstlane'd wv) -> scalar cache,
// freeing the vector/LDS pipes; x is read-only so the scalar path is safe.
// W stream is register double-buffered (w0/w1) so loads for i+1 issue before
// compute of i -> breaks the load->compute lockstep that stalled R8.
template<bool UNIFORM>
__device__ __forceinline__ void iter_body(
        const float* __restrict__ x, const float* __restrict__ W,
        const float* __restrict__ vsg, float* __restrict__ partial,
        int p, int b0, int i0, int t)
{
    const int lane = t & 63;
    const int wv   = __builtin_amdgcn_readfirstlane(t >> 6);
    const int k    = lane >> 2;             // output capsule
    const int e4   = (lane & 3) << 2;       // first of 4 output dims
    const int bw   = b0 + (wv << 2);        // this wave's first batch

    float4 vb[4];
    if (!UNIFORM) {
        #pragma unroll
        for (int b4 = 0; b4 < 4; ++b4)
            vb[b4] = *(const float4*)(vsg + ((bw + b4) << 8) + k * 16 + e4);
    }

    float4 acc[4];
    #pragma unroll
    for (int b4 = 0; b4 < 4; ++b4) acc[b4] = make_float4(0.f, 0.f, 0.f, 0.f);

    float4 w0[8], w1[8];
    load_w(w0, W, i0, k, e4);

    #pragma unroll
    for (int ii = 0; ii < IB; ii += 2) {
        // prefetch i+1 into the other buffer before computing i
        load_w(w1, W, i0 + ii + 1, k, e4);

        #pragma unroll
        for (int half = 0; half < 2; ++half) {
            const int i = i0 + ii + half;
            const float4 (&w)[8] = half ? w1 : w0;

            #pragma unroll
            for (int b4 = 0; b4 < 4; ++b4) {
                // wave-uniform address -> scalar loads (s_load_dwordx4)
                const float* xp = x + ((size_t)(bw + b4) * In + i) * Dk;
                const float4 x0 = *(const float4*)xp;
                const float4 x1 = *(const float4*)(xp + 4);
                const float xs8[8] = {x0.x, x0.y, x0.z, x0.w,
                                      x1.x, x1.y, x1.z, x1.w};

                float4 uh = make_float4(0.f, 0.f, 0.f, 0.f);
                #pragma unroll
                for (int d = 0; d < 8; ++d) {
                    uh.x = fmaf(xs8[d], w[d].x, uh.x);
                    uh.y = fmaf(xs8[d], w[d].y, uh.y);
                    uh.z = fmaf(xs8[d], w[d].z, uh.z);
                    uh.w = fmaf(xs8[d], w[d].w, uh.w);
                }

                if (UNIFORM) {
                    acc[b4].x += uh.x; acc[b4].y += uh.y;
                    acc[b4].z += uh.z; acc[b4].w += uh.w;
                } else {
                    float tt = uh.x * vb[b4].x + uh.y * vb[b4].y
                             + uh.z * vb[b4].z + uh.w * vb[b4].w;
                    tt = dpp_add<0xB1>(tt);           // e-reduce: quad xor 1
                    tt = dpp_add<0x4E>(tt);           // e-reduce: quad xor 2
                    const float pe = __expf(tt);      // no max-sub: |tt| small
                    float den = dpp_add<0x124>(pe);   // k-sum in row: ror 4
                    den = dpp_add<0x128>(den);        // k-sum in row: ror 8
                    den += __shfl_xor(den, 16);       // cross-row
                    den += __shfl_xor(den, 32);
                    const float c = pe * __builtin_amdgcn_rcpf(den);
                    acc[b4].x = fmaf(c, uh.x, acc[b4].x);
                    acc[b4].y = fmaf(c, uh.y, acc[b4].y);
                    acc[b4].z = fmaf(c, uh.z, acc[b4].z);
                    acc[b4].w = fmaf(c, uh.w, acc[b4].w);
                }
            }
            // prefetch i+2 into w0 after consuming it, before computing i+1
            if (half == 0 && ii + 2 < IB) load_w(w0, W, i0 + ii + 2, k, e4);
        }
    }

    #pragma unroll
    for (int b4 = 0; b4 < 4; ++b4)
        *(float4*)(partial + ((size_t)(bw + b4) * P + p) * 256 + k * 16 + e4) = acc[b4];
}

// Sum the P=256 partials, squash, optional vprev add. rb = 0..255:
// b = rb>>2, element-quarter q = rb&3; 4 p-groups of 64 p's, combined in LDS.
__device__ __forceinline__ void reduce_phase(float* red,
        const float* __restrict__ partial, float scale,
        const float* __restrict__ vprev, float* __restrict__ vout, int rb, int t)
{
    const int b  = rb >> 2;
    const int q  = rb & 3;
    const int t4 = t & 63;
    const int pg = t >> 6;
    const int el = (q << 6) + t4;           // element 0..255 (= k*16+e)
    const float* pp = partial + (size_t)b * (P * 256) + ((pg << 6) * 256) + el;

    float s0 = 0.f, s1 = 0.f, s2 = 0.f, s3 = 0.f;
    #pragma unroll 4
    for (int j = 0; j < 64; j += 4) {
        s0 += pp[(j + 0) * 256];
        s1 += pp[(j + 1) * 256];
        s2 += pp[(j + 2) * 256];
        s3 += pp[(j + 3) * 256];
    }
    red[(pg << 6) + t4] = (s0 + s1) + (s2 + s3);
    __syncthreads();

    if (t < 64) {
        const float val = (red[t4] + red[64 + t4] + red[128 + t4] + red[192 + t4]) * scale;
        float sq = val * val;                // e = el & 15 = t4 & 15
        sq += __shfl_xor(sq, 1);
        sq += __shfl_xor(sq, 2);
        sq += __shfl_xor(sq, 4);
        sq += __shfl_xor(sq, 8);
        const float f = sq / ((1.0f + sq) * sqrtf(sq + EPS));
        float v = val * f;
        if (vprev) v += vprev[(b << 8) + el];
        vout[(b << 8) + el] = v;
    }
    __syncthreads();
}

// XCD-bijective tile mapping: physical XCD = bid&7 (round-robin dispatch);
// each XCD owns a contiguous 32-chunk p-range (2 MB of W -> L2-resident) and
// all 4 batch-group duplicates of a p run on the same XCD.
__device__ __forceinline__ void tile_map(int bid, int& p, int& b0, int& i0) {
    const int xcd = bid & 7;
    const int j   = bid >> 3;               // 0..127
    p  = xcd * PPX + (j & (PPX - 1));       // bijective: 8 x 32 x 4 = 1024
    b0 = (j >> 5) * BSET;                   // 0..3 batch groups
    i0 = p * IB;
}

// ---------------- fused cooperative kernel (1 KB LDS) ----------------
__global__ __launch_bounds__(256)
void caps_fused(const float* __restrict__ x, const float* __restrict__ W,
                float* __restrict__ partial, float* __restrict__ v0,
                float* __restrict__ vs, float* __restrict__ out)
{
    cg::grid_group grid = cg::this_grid();
    __shared__ __align__(16) float red[256];

    const int t = threadIdx.x, bid = blockIdx.x;
    int p, b0, i0;
    tile_map(bid, p, b0, i0);

    // r = 0: uniform coupling (1/16 folded into reduce scale)
    iter_body<true>(x, W, nullptr, partial, p, b0, i0, t);
    grid.sync();
    if (bid < 256) reduce_phase(red, partial, 1.0f / 16.0f, nullptr, v0, bid, t);
    grid.sync();

    // r = 1: logits = dot(u_hat, v0);  vs = v0 + v1
    iter_body<false>(x, W, v0, partial, p, b0, i0, t);
    grid.sync();
    if (bid < 256) reduce_phase(red, partial, 1.0f, v0, vs, bid, t);
    grid.sync();

    // r = 2: logits = dot(u_hat, v0 + v1); final squash -> out
    iter_body<false>(x, W, vs, partial, p, b0, i0, t);
    grid.sync();
    if (bid < 256) reduce_phase(red, partial, 1.0f, nullptr, out, bid, t);
}

// ---------------- fallback: same phases as separate kernels ----------------
template<bool UNIFORM>
__global__ __launch_bounds__(256)
void caps_iter_g(const float* __restrict__ x, const float* __restrict__ W,
                 const float* __restrict__ vsg, float* __restrict__ partial)
{
    int p, b0, i0;
    tile_map(blockIdx.x, p, b0, i0);
    iter_body<UNIFORM>(x, W, vsg, partial, p, b0, i0, threadIdx.x);
}

__global__ __launch_bounds__(256)
void caps_reduce_g(const float* __restrict__ partial, float scale,
                   const float* __restrict__ vprev, float* __restrict__ vout)
{
    __shared__ __align__(16) float red[256];
    reduce_phase(red, partial, scale, vprev, vout, blockIdx.x, threadIdx.x);
}

extern "C" void kernel_launch(void* const* d_in, const int* in_sizes, int n_in,
                              void* d_out, int out_size, void* d_ws, size_t ws_size,
                              hipStream_t stream) {
    const float* x = (const float*)d_in[0];   // [64, 2048, 8]
    const float* W = (const float*)d_in[1];   // [2048, 16, 8, 16]
    float* out = (float*)d_out;               // [64, 16, 16]
    float* ws  = (float*)d_ws;

    float* v0      = ws;                      // [64,16,16]
    float* vs      = ws + 16384;              // v0 + v1
    float* partial = ws + 32768;              // [64][256][256] = 16.8 MB

    // Host-side co-residency gate (capture-safe: no stream ops). Only launch
    // cooperatively if the runtime agrees all 1024 blocks fit.
    int dev = 0;
    hipGetDevice(&dev);
    int numCU = 0;
    hipDeviceGetAttribute(&numCU, hipDeviceAttributeMultiprocessorCount, dev);
    int maxB = 0;
    hipError_t oe = hipOccupancyMaxActiveBlocksPerMultiprocessor(
        &maxB, (const void*)caps_fused, 256, 0);
    const bool coop = (oe == hipSuccess) && numCU > 0 &&
                      ((long)maxB * numCU >= BLOCKS);

    if (coop) {
        void* args[] = { (void*)&x, (void*)&W, (void*)&partial,
                         (void*)&v0, (void*)&vs, (void*)&out };
        hipLaunchCooperativeKernel((void*)caps_fused, dim3(BLOCKS), dim3(256),
                                   args, 0, stream);
    } else {
        caps_iter_g<true ><<<BLOCKS, 256, 0, stream>>>(x, W, nullptr, partial);
        caps_reduce_g<<<256, 256, 0, stream>>>(partial, 1.0f / 16.0f, nullptr, v0);
        caps_iter_g<false><<<BLOCKS, 256, 0, stream>>>(x, W, v0, partial);
        caps_reduce_g<<<256, 256, 0, stream>>>(partial, 1.0f, v0, vs);
        caps_iter_g<false><<<BLOCKS, 256, 0, stream>>>(x, W, vs, partial);
        caps_reduce_g<<<256, 256, 0, stream>>>(partial, 1.0f, nullptr, out);
    }
}

// Round 11
// 79.073 us; speedup vs baseline: 1.0871x; 1.0871x over previous
//
#include <hip/hip_runtime.h>
#include <hip/hip_cooperative_groups.h>
#include <cstddef>

namespace cg = cooperative_groups;

// Problem constants (from reference)
constexpr int Bn = 64;     // batch
constexpr int In = 2048;   // input capsules
constexpr int Dk = 8;      // input dim
constexpr int Kc = 16;     // output capsules
constexpr int En = 16;     // output dim
constexpr float EPS = 1e-7f;

// Decomposition (R8-proven tile, 8 waves/block): block = (p, g) tile of
// 8 i's x 16 batches; wave owns 2 batches x all 8 i's -> disjoint outputs,
// barrier-free iter. 1024 blocks x 512 thr = 32 waves/CU (2x R8's residency,
// same grid.sync count/cost).
constexpr int IB   = 8;            // i's per block
constexpr int P    = In / IB;      // 256 i-chunks
constexpr int BSET = 16;           // batches per block (2 per wave, 8 waves)
constexpr int NBG  = Bn / BSET;    // 4 batch groups
constexpr int BLOCKS = P * NBG;    // 1024
constexpr int THREADS = 512;       // 8 waves
constexpr int PPX  = P / 8;        // 32 p-chunks per XCD

// DPP cross-lane add on the VALU pipe (no LDS-pipe traffic).
// ctrl: 0xB1 = quad_perm xor1, 0x4E = quad_perm xor2, 0x124/0x128 = row_ror 4/8
template<int CTRL>
__device__ __forceinline__ float dpp_add(float v) {
    int r = __builtin_amdgcn_update_dpp(0, __float_as_int(v), CTRL, 0xF, 0xF, true);
    return v + __int_as_float(r);
}

// One routing iteration for a (p, g) tile. x tile staged in smemx[0,1024) as
// [bl][il][d]. Wave wv handles batches bw..bw+1 across all 8 i's; acc[2] =
// 8 VGPR live, W single-buffered w[8] (R9's inner loop measured 52 VGPR;
// R10 lesson: double-buffering W costs more occupancy than it saves).
// Barrier-free; one plain float4 store per (batch, lane).
template<bool UNIFORM>
__device__ __forceinline__ void iter_body(const float* __restrict__ smemx,
        const float* __restrict__ W, const float* __restrict__ vsg,
        float* __restrict__ partial, int p, int b0, int i0, int t)
{
    const int lane = t & 63;
    const int wv   = t >> 6;                // 0..7
    const int k    = lane >> 2;             // output capsule
    const int e4   = (lane & 3) << 2;       // first of 4 output dims
    const int bw   = b0 + (wv << 1);        // this wave's first batch

    float4 vb[2];
    if (!UNIFORM) {
        #pragma unroll
        for (int b4 = 0; b4 < 2; ++b4)
            vb[b4] = *(const float4*)(vsg + ((bw + b4) << 8) + k * 16 + e4);
    }

    float4 acc[2];
    #pragma unroll
    for (int b4 = 0; b4 < 2; ++b4) acc[b4] = make_float4(0.f, 0.f, 0.f, 0.f);

    #pragma unroll 1
    for (int ii = 0; ii < IB; ++ii) {
        const int i = i0 + ii;
        const float* wp = W + (size_t)i * (Kc * Dk * En) + k * (Dk * En) + e4;
        float4 w[8];
        #pragma unroll
        for (int d = 0; d < 8; ++d) w[d] = *(const float4*)(wp + d * En);

        #pragma unroll
        for (int b4 = 0; b4 < 2; ++b4) {
            const int bl = (wv << 1) + b4;
            const float* xp = smemx + (((bl << 3) + ii) << 3);  // [bl][ii][*]
            const float4 x0 = *(const float4*)xp;
            const float4 x1 = *(const float4*)(xp + 4);
            const float xs8[8] = {x0.x, x0.y, x0.z, x0.w, x1.x, x1.y, x1.z, x1.w};

            float4 uh = make_float4(0.f, 0.f, 0.f, 0.f);
            #pragma unroll
            for (int d = 0; d < 8; ++d) {
                uh.x = fmaf(xs8[d], w[d].x, uh.x);
                uh.y = fmaf(xs8[d], w[d].y, uh.y);
                uh.z = fmaf(xs8[d], w[d].z, uh.z);
                uh.w = fmaf(xs8[d], w[d].w, uh.w);
            }

            if (UNIFORM) {
                acc[b4].x += uh.x; acc[b4].y += uh.y;
                acc[b4].z += uh.z; acc[b4].w += uh.w;
            } else {
                float tt = uh.x * vb[b4].x + uh.y * vb[b4].y
                         + uh.z * vb[b4].z + uh.w * vb[b4].w;
                tt = dpp_add<0xB1>(tt);           // e-reduce: quad xor 1
                tt = dpp_add<0x4E>(tt);           // e-reduce: quad xor 2
                const float pe = __expf(tt);      // no max-sub: |tt| small
                float den = dpp_add<0x124>(pe);   // k-sum in row: ror 4
                den = dpp_add<0x128>(den);        // k-sum in row: ror 8
                den += __shfl_xor(den, 16);       // cross-row
                den += __shfl_xor(den, 32);
                const float c = pe * __builtin_amdgcn_rcpf(den);
                acc[b4].x = fmaf(c, uh.x, acc[b4].x);
                acc[b4].y = fmaf(c, uh.y, acc[b4].y);
                acc[b4].z = fmaf(c, uh.z, acc[b4].z);
                acc[b4].w = fmaf(c, uh.w, acc[b4].w);
            }
        }
    }

    #pragma unroll
    for (int b4 = 0; b4 < 2; ++b4)
        *(float4*)(partial + ((size_t)(bw + b4) * P + p) * 256 + k * 16 + e4) = acc[b4];
}

// Sum the P=256 partials, squash, optional vprev add. rb = 0..255:
// b = rb>>2, element-quarter q = rb&3. 512 threads = 8 p-groups of 32 p's,
// combined via red[512].
__device__ __forceinline__ void reduce_phase(float* red,
        const float* __restrict__ partial, float scale,
        const float* __restrict__ vprev, float* __restrict__ vout, int rb, int t)
{
    const int b  = rb >> 2;
    const int q  = rb & 3;
    const int t4 = t & 63;
    const int pg = t >> 6;                  // 0..7 -> 32 p's each
    const int el = (q << 6) + t4;           // element 0..255 (= k*16+e)
    const float* pp = partial + (size_t)b * (P * 256) + ((pg << 5) * 256) + el;

    float s0 = 0.f, s1 = 0.f, s2 = 0.f, s3 = 0.f;
    #pragma unroll 4
    for (int j = 0; j < 32; j += 4) {
        s0 += pp[(j + 0) * 256];
        s1 += pp[(j + 1) * 256];
        s2 += pp[(j + 2) * 256];
        s3 += pp[(j + 3) * 256];
    }
    red[(pg << 6) + t4] = (s0 + s1) + (s2 + s3);
    __syncthreads();

    if (t < 64) {
        const float v0 = red[t4]       + red[64 + t4];
        const float v1 = red[128 + t4] + red[192 + t4];
        const float v2 = red[256 + t4] + red[320 + t4];
        const float v3 = red[384 + t4] + red[448 + t4];
        const float val = ((v0 + v1) + (v2 + v3)) * scale;
        float sq = val * val;                // e = el & 15 = t4 & 15
        sq += __shfl_xor(sq, 1);
        sq += __shfl_xor(sq, 2);
        sq += __shfl_xor(sq, 4);
        sq += __shfl_xor(sq, 8);
        const float f = sq / ((1.0f + sq) * sqrtf(sq + EPS));
        float v = val * f;
        if (vprev) v += vprev[(b << 8) + el];
        vout[(b << 8) + el] = v;
    }
    __syncthreads();
}

// XCD-bijective tile mapping: physical XCD = bid&7 (round-robin dispatch);
// each XCD owns a contiguous 32-chunk p-range and all 4 batch-group
// duplicates of a p run on the same XCD.
__device__ __forceinline__ void tile_map(int bid, int& p, int& b0, int& i0) {
    const int xcd = bid & 7;
    const int j   = bid >> 3;               // 0..127
    p  = xcd * PPX + (j & (PPX - 1));       // bijective: 8 x 32 x 4 = 1024
    b0 = (j >> 5) * BSET;                   // 0..3 batch groups
    i0 = p * IB;
}

// Stage x[b0..b0+15][i0..i0+7][0..7] -> smem [bl][il][d] (256 float4).
__device__ __forceinline__ void stage_x(float* smem, const float* __restrict__ x,
                                        int b0, int i0, int t) {
    if (t < 256) {
        const int bl = t >> 4;              // 0..15
        const int r  = t & 15;              // float4 within the bl row
        ((float4*)smem)[t] = *(const float4*)(x + ((size_t)(b0 + bl) * In + i0) * Dk + (r << 2));
    }
}

// ---------------- fused cooperative kernel (6 KB LDS) ----------------
__global__ __launch_bounds__(THREADS)
void caps_fused(const float* __restrict__ x, const float* __restrict__ W,
                float* __restrict__ partial, float* __restrict__ v0,
                float* __restrict__ vs, float* __restrict__ out)
{
    cg::grid_group grid = cg::this_grid();
    __shared__ __align__(16) float smem[1536];   // x [0,1024) | red [1024,1536)

    const int t = threadIdx.x, bid = blockIdx.x;
    int p, b0, i0;
    tile_map(bid, p, b0, i0);

    stage_x(smem, x, b0, i0, t);        // once, reused by all 3 iterations
    __syncthreads();

    // r = 0: uniform coupling (1/16 folded into reduce scale)
    iter_body<true>(smem, W, nullptr, partial, p, b0, i0, t);
    grid.sync();
    if (bid < 256) reduce_phase(smem + 1024, partial, 1.0f / 16.0f, nullptr, v0, bid, t);
    grid.sync();

    // r = 1: logits = dot(u_hat, v0);  vs = v0 + v1
    iter_body<false>(smem, W, v0, partial, p, b0, i0, t);
    grid.sync();
    if (bid < 256) reduce_phase(smem + 1024, partial, 1.0f, v0, vs, bid, t);
    grid.sync();

    // r = 2: logits = dot(u_hat, v0 + v1); final squash -> out
    iter_body<false>(smem, W, vs, partial, p, b0, i0, t);
    grid.sync();
    if (bid < 256) reduce_phase(smem + 1024, partial, 1.0f, nullptr, out, bid, t);
}

// ---------------- fallback: same phases as separate kernels ----------------
template<bool UNIFORM>
__global__ __launch_bounds__(THREADS)
void caps_iter_g(const float* __restrict__ x, const float* __restrict__ W,
                 const float* __restrict__ vsg, float* __restrict__ partial)
{
    __shared__ __align__(16) float smem[1024];
    const int t = threadIdx.x;
    int p, b0, i0;
    tile_map(blockIdx.x, p, b0, i0);
    stage_x(smem, x, b0, i0, t);
    __syncthreads();
    iter_body<UNIFORM>(smem, W, vsg, partial, p, b0, i0, t);
}

__global__ __launch_bounds__(THREADS)
void caps_reduce_g(const float* __restrict__ partial, float scale,
                   const float* __restrict__ vprev, float* __restrict__ vout)
{
    __shared__ __align__(16) float red[512];
    reduce_phase(red, partial, scale, vprev, vout, blockIdx.x, threadIdx.x);
}

extern "C" void kernel_launch(void* const* d_in, const int* in_sizes, int n_in,
                              void* d_out, int out_size, void* d_ws, size_t ws_size,
                              hipStream_t stream) {
    const float* x = (const float*)d_in[0];   // [64, 2048, 8]
    const float* W = (const float*)d_in[1];   // [2048, 16, 8, 16]
    float* out = (float*)d_out;               // [64, 16, 16]
    float* ws  = (float*)d_ws;

    float* v0      = ws;                      // [64,16,16]
    float* vs      = ws + 16384;              // v0 + v1
    float* partial = ws + 32768;              // [64][256][256] = 16.8 MB

    // Host-side co-residency gate (capture-safe: no stream ops). Only launch
    // cooperatively if the runtime agrees all 1024 blocks fit.
    int dev = 0;
    hipGetDevice(&dev);
    int numCU = 0;
    hipDeviceGetAttribute(&numCU, hipDeviceAttributeMultiprocessorCount, dev);
    int maxB = 0;
    hipError_t oe = hipOccupancyMaxActiveBlocksPerMultiprocessor(
        &maxB, (const void*)caps_fused, THREADS, 0);
    const bool coop = (oe == hipSuccess) && numCU > 0 &&
                      ((long)maxB * numCU >= BLOCKS);

    if (coop) {
        void* args[] = { (void*)&x, (void*)&W, (void*)&partial,
                         (void*)&v0, (void*)&vs, (void*)&out };
        hipLaunchCooperativeKernel((void*)caps_fused, dim3(BLOCKS), dim3(THREADS),
                                   args, 0, stream);
    } else {
        caps_iter_g<true ><<<BLOCKS, THREADS, 0, stream>>>(x, W, nullptr, partial);
        caps_reduce_g<<<256, THREADS, 0, stream>>>(partial, 1.0f / 16.0f, nullptr, v0);
        caps_iter_g<false><<<BLOCKS, THREADS, 0, stream>>>(x, W, v0, partial);
        caps_reduce_g<<<256, THREADS, 0, stream>>>(partial, 1.0f, v0, vs);
        caps_iter_g<false><<<BLOCKS, THREADS, 0, stream>>>(x, W, vs, partial);
        caps_reduce_g<<<256, THREADS, 0, stream>>>(partial, 1.0f, nullptr, out);
    }
}

// Round 12
// 65.314 us; speedup vs baseline: 1.3161x; 1.2106x over previous
//
#include <hip/hip_runtime.h>
#include <hip/hip_cooperative_groups.h>
#include <cstddef>

namespace cg = cooperative_groups;

// Problem constants (from reference)
constexpr int Bn = 64;     // batch
constexpr int In = 2048;   // input capsules
constexpr int Dk = 8;      // input dim
constexpr int Kc = 16;     // output capsules
constexpr int En = 16;     // output dim
constexpr float EPS = 1e-7f;

// Decomposition (R8-proven optimum of W-amortization x occupancy):
// block = (p, g) tile of 8 i's x 16 batches, 4 waves; wave owns 4 batches x
// all 8 i's -> disjoint outputs, barrier-free iter. 1024 blocks co-resident.
constexpr int IB   = 8;            // i's per block
constexpr int P    = In / IB;      // 256 i-chunks
constexpr int BSET = 16;           // batches per block (4 per wave)
constexpr int NBG  = Bn / BSET;    // 4 batch groups
constexpr int BLOCKS = P * NBG;    // 1024
constexpr int THREADS = 256;       // 4 waves
constexpr int PPX  = P / 8;        // 32 p-chunks per XCD (2 MB of W < 4 MB L2)

// DPP cross-lane add on the VALU pipe (no LDS-pipe traffic).
// ctrl: 0xB1 = quad_perm xor1, 0x4E = quad_perm xor2, 0x124/0x128 = row_ror 4/8
template<int CTRL>
__device__ __forceinline__ float dpp_add(float v) {
    int r = __builtin_amdgcn_update_dpp(0, __float_as_int(v), CTRL, 0xF, 0xF, true);
    return v + __int_as_float(r);
}

// One routing iteration for a (p, g) tile. x tile staged in smemx[0,1024) as
// [bl][il][d]. Wave wv handles batches bw..bw+3 across all 8 i's; acc[4] =
// 16 VGPR (R4/R5 lesson: live set structurally small, all indices static,
// NO launch_bounds VGPR cap). i-loop at unroll 2: the compiler software-
// pipelines i+1's W-load burst under i's ~340-cycle compute (R8 ran unroll 1
// and stalled at VALUBusy 48%; R10's manual double-buffer blew VGPR to 192 --
// unroll 2 gets the pipelining with only one extra w[8] set, ~+32 VGPR).
template<bool UNIFORM>
__device__ __forceinline__ void iter_body(const float* __restrict__ smemx,
        const float* __restrict__ W, const float* __restrict__ vsg,
        float* __restrict__ partial, int p, int b0, int i0, int t)
{
    const int lane = t & 63;
    const int wv   = t >> 6;                // 0..3
    const int k    = lane >> 2;             // output capsule
    const int e4   = (lane & 3) << 2;       // first of 4 output dims
    const int bw   = b0 + (wv << 2);        // this wave's first batch

    float4 vb[4];
    if (!UNIFORM) {
        #pragma unroll
        for (int b4 = 0; b4 < 4; ++b4)
            vb[b4] = *(const float4*)(vsg + ((bw + b4) << 8) + k * 16 + e4);
    }

    float4 acc[4];
    #pragma unroll
    for (int b4 = 0; b4 < 4; ++b4) acc[b4] = make_float4(0.f, 0.f, 0.f, 0.f);

    #pragma unroll 2
    for (int ii = 0; ii < IB; ++ii) {
        const int i = i0 + ii;
        const float* wp = W + (size_t)i * (Kc * Dk * En) + k * (Dk * En) + e4;
        float4 w[8];
        #pragma unroll
        for (int d = 0; d < 8; ++d) w[d] = *(const float4*)(wp + d * En);

        #pragma unroll
        for (int b4 = 0; b4 < 4; ++b4) {
            const int bl = (wv << 2) + b4;
            const float* xp = smemx + (((bl << 3) + ii) << 3);  // [bl][ii][*]
            const float4 x0 = *(const float4*)xp;
            const float4 x1 = *(const float4*)(xp + 4);
            const float xs8[8] = {x0.x, x0.y, x0.z, x0.w, x1.x, x1.y, x1.z, x1.w};

            float4 uh = make_float4(0.f, 0.f, 0.f, 0.f);
            #pragma unroll
            for (int d = 0; d < 8; ++d) {
                uh.x = fmaf(xs8[d], w[d].x, uh.x);
                uh.y = fmaf(xs8[d], w[d].y, uh.y);
                uh.z = fmaf(xs8[d], w[d].z, uh.z);
                uh.w = fmaf(xs8[d], w[d].w, uh.w);
            }

            if (UNIFORM) {
                acc[b4].x += uh.x; acc[b4].y += uh.y;
                acc[b4].z += uh.z; acc[b4].w += uh.w;
            } else {
                float tt = uh.x * vb[b4].x + uh.y * vb[b4].y
                         + uh.z * vb[b4].z + uh.w * vb[b4].w;
                tt = dpp_add<0xB1>(tt);           // e-reduce: quad xor 1
                tt = dpp_add<0x4E>(tt);           // e-reduce: quad xor 2
                const float pe = __expf(tt);      // no max-sub: |tt| small
                float den = dpp_add<0x124>(pe);   // k-sum in row: ror 4
                den = dpp_add<0x128>(den);        // k-sum in row: ror 8
                den += __shfl_xor(den, 16);       // cross-row
                den += __shfl_xor(den, 32);
                const float c = pe * __builtin_amdgcn_rcpf(den);
                acc[b4].x = fmaf(c, uh.x, acc[b4].x);
                acc[b4].y = fmaf(c, uh.y, acc[b4].y);
                acc[b4].z = fmaf(c, uh.z, acc[b4].z);
                acc[b4].w = fmaf(c, uh.w, acc[b4].w);
            }
        }
    }

    #pragma unroll
    for (int b4 = 0; b4 < 4; ++b4)
        *(float4*)(partial + ((size_t)(bw + b4) * P + p) * 256 + k * 16 + e4) = acc[b4];
}

// Sum the P=256 partials, squash, optional vprev add. rb = 0..255:
// b = rb>>2, element-quarter q = rb&3; 4 p-groups of 64 p's, combined in LDS.
__device__ __forceinline__ void reduce_phase(float* red,
        const float* __restrict__ partial, float scale,
        const float* __restrict__ vprev, float* __restrict__ vout, int rb, int t)
{
    const int b  = rb >> 2;
    const int q  = rb & 3;
    const int t4 = t & 63;
    const int pg = t >> 6;
    const int el = (q << 6) + t4;           // element 0..255 (= k*16+e)
    const float* pp = partial + (size_t)b * (P * 256) + ((pg << 6) * 256) + el;

    float s0 = 0.f, s1 = 0.f, s2 = 0.f, s3 = 0.f;
    #pragma unroll 4
    for (int j = 0; j < 64; j += 4) {
        s0 += pp[(j + 0) * 256];
        s1 += pp[(j + 1) * 256];
        s2 += pp[(j + 2) * 256];
        s3 += pp[(j + 3) * 256];
    }
    red[(pg << 6) + t4] = (s0 + s1) + (s2 + s3);
    __syncthreads();

    if (t < 64) {
        const float val = (red[t4] + red[64 + t4] + red[128 + t4] + red[192 + t4]) * scale;
        float sq = val * val;                // e = el & 15 = t4 & 15
        sq += __shfl_xor(sq, 1);
        sq += __shfl_xor(sq, 2);
        sq += __shfl_xor(sq, 4);
        sq += __shfl_xor(sq, 8);
        const float f = sq / ((1.0f + sq) * sqrtf(sq + EPS));
        float v = val * f;
        if (vprev) v += vprev[(b << 8) + el];
        vout[(b << 8) + el] = v;
    }
    __syncthreads();
}

// XCD-bijective tile mapping: physical XCD = bid&7 (round-robin dispatch);
// each XCD owns a contiguous 32-chunk p-range (2 MB of W -> L2-resident) and
// all 4 batch-group duplicates of a p run on the same XCD.
__device__ __forceinline__ void tile_map(int bid, int& p, int& b0, int& i0) {
    const int xcd = bid & 7;
    const int j   = bid >> 3;               // 0..127
    p  = xcd * PPX + (j & (PPX - 1));       // bijective: 8 x 32 x 4 = 1024
    b0 = (j >> 5) * BSET;                   // 0..3 batch groups
    i0 = p * IB;
}

// Stage x[b0..b0+15][i0..i0+7][0..7] -> smem [bl][il][d] (256 float4).
__device__ __forceinline__ void stage_x(float* smem, const float* __restrict__ x,
                                        int b0, int i0, int t) {
    const int bl = t >> 4;                  // 0..15
    const int r  = t & 15;                  // float4 within the bl row
    ((float4*)smem)[t] = *(const float4*)(x + ((size_t)(b0 + bl) * In + i0) * Dk + (r << 2));
}

// ---------------- fused cooperative kernel (5 KB LDS) ----------------
__global__ __launch_bounds__(THREADS)
void caps_fused(const float* __restrict__ x, const float* __restrict__ W,
                float* __restrict__ partial, float* __restrict__ v0,
                float* __restrict__ vs, float* __restrict__ out)
{
    cg::grid_group grid = cg::this_grid();
    __shared__ __align__(16) float smem[1280];   // x [0,1024) | red [1024,1280)

    const int t = threadIdx.x, bid = blockIdx.x;
    int p, b0, i0;
    tile_map(bid, p, b0, i0);

    stage_x(smem, x, b0, i0, t);        // once, reused by all 3 iterations
    __syncthreads();

    // r = 0: uniform coupling (1/16 folded into reduce scale)
    iter_body<true>(smem, W, nullptr, partial, p, b0, i0, t);
    grid.sync();
    if (bid < 256) reduce_phase(smem + 1024, partial, 1.0f / 16.0f, nullptr, v0, bid, t);
    grid.sync();

    // r = 1: logits = dot(u_hat, v0);  vs = v0 + v1
    iter_body<false>(smem, W, v0, partial, p, b0, i0, t);
    grid.sync();
    if (bid < 256) reduce_phase(smem + 1024, partial, 1.0f, v0, vs, bid, t);
    grid.sync();

    // r = 2: logits = dot(u_hat, v0 + v1); final squash -> out
    iter_body<false>(smem, W, vs, partial, p, b0, i0, t);
    grid.sync();
    if (bid < 256) reduce_phase(smem + 1024, partial, 1.0f, nullptr, out, bid, t);
}

// ---------------- fallback: same phases as separate kernels ----------------
template<bool UNIFORM>
__global__ __launch_bounds__(THREADS)
void caps_iter_g(const float* __restrict__ x, const float* __restrict__ W,
                 const float* __restrict__ vsg, float* __restrict__ partial)
{
    __shared__ __align__(16) float smem[1024];
    const int t = threadIdx.x;
    int p, b0, i0;
    tile_map(blockIdx.x, p, b0, i0);
    stage_x(smem, x, b0, i0, t);
    __syncthreads();
    iter_body<UNIFORM>(smem, W, vsg, partial, p, b0, i0, t);
}

__global__ __launch_bounds__(THREADS)
void caps_reduce_g(const float* __restrict__ partial, float scale,
                   const float* __restrict__ vprev, float* __restrict__ vout)
{
    __shared__ __align__(16) float red[256];
    reduce_phase(red, partial, scale, vprev, vout, blockIdx.x, threadIdx.x);
}

extern "C" void kernel_launch(void* const* d_in, const int* in_sizes, int n_in,
                              void* d_out, int out_size, void* d_ws, size_t ws_size,
                              hipStream_t stream) {
    const float* x = (const float*)d_in[0];   // [64, 2048, 8]
    const float* W = (const float*)d_in[1];   // [2048, 16, 8, 16]
    float* out = (float*)d_out;               // [64, 16, 16]
    float* ws  = (float*)d_ws;

    float* v0      = ws;                      // [64,16,16]
    float* vs      = ws + 16384;              // v0 + v1
    float* partial = ws + 32768;              // [64][256][256] = 16.8 MB

    // Host-side co-residency gate (capture-safe: no stream ops). Only launch
    // cooperatively if the runtime agrees all 1024 blocks fit.
    int dev = 0;
    hipGetDevice(&dev);
    int numCU = 0;
    hipDeviceGetAttribute(&numCU, hipDeviceAttributeMultiprocessorCount, dev);
    int maxB = 0;
    hipError_t oe = hipOccupancyMaxActiveBlocksPerMultiprocessor(
        &maxB, (const void*)caps_fused, THREADS, 0);
    const bool coop = (oe == hipSuccess) && numCU > 0 &&
                      ((long)maxB * numCU >= BLOCKS);

    if (coop) {
        void* args[] = { (void*)&x, (void*)&W, (void*)&partial,
                         (void*)&v0, (void*)&vs, (void*)&out };
        hipLaunchCooperativeKernel((void*)caps_fused, dim3(BLOCKS), dim3(THREADS),
                                   args, 0, stream);
    } else {
        caps_iter_g<true ><<<BLOCKS, THREADS, 0, stream>>>(x, W, nullptr, partial);
        caps_reduce_g<<<256, THREADS, 0, stream>>>(partial, 1.0f / 16.0f, nullptr, v0);
        caps_iter_g<false><<<BLOCKS, THREADS, 0, stream>>>(x, W, v0, partial);
        caps_reduce_g<<<256, THREADS, 0, stream>>>(partial, 1.0f, v0, vs);
        caps_iter_g<false><<<BLOCKS, THREADS, 0, stream>>>(x, W, vs, partial);
        caps_reduce_g<<<256, THREADS, 0, stream>>>(partial, 1.0f, nullptr, out);
    }
}